// Round 5
// baseline (245.447 us; speedup 1.0000x reference)
//
#include <hip/hip_runtime.h>

#define T_TOK 16384
#define H 2048
#define HV (H / 4)       // float4 per row = 512
#define NE 8
#define TPG 4            // tokens per wave
#define ALPHA 0.01f
#define TOPK 2
#define NBLK 1024        // 1024 blk * 4 waves * 4 tok = 16384 tokens
#define NREP 4           // DIAGNOSTIC: repeat work so dispatch > 77us -> top-5 counters

// out layout (floats): [0, 2T) idx as float, [2T, 4T) weights, [4T] aux loss
// ws layout (floats):  per-block partials, ws[b*16 + e] = sum(scores_e),
//                      ws[b*16 + 8 + e] = topk count_e

__global__ __launch_bounds__(256, 4) void gate_main(
    const float* __restrict__ x, const float* __restrict__ w,
    float* __restrict__ out, float* __restrict__ ws)
{
    __shared__ float s_pi[NE];
    __shared__ float s_cnt[NE];

    const int tid  = threadIdx.x;
    const int lane = tid & 63;
    const int wave = tid >> 6;
    const int t0   = (blockIdx.x * 4 + wave) * TPG;

    const float4* __restrict__ xv = (const float4*)x;
    const float4* __restrict__ wv = (const float4*)w;
    const float4* xp = xv + (size_t)t0 * HV + lane;
    const float4* wp = wv + lane;

#pragma unroll 1
    for (int rep = 0; rep < NREP; rep++) {
        __syncthreads();
        if (tid < NE) { s_pi[tid] = 0.f; s_cnt[tid] = 0.f; }
        __syncthreads();

        float acc[NE][TPG];
#pragma unroll
        for (int e = 0; e < NE; e++)
#pragma unroll
            for (int t = 0; t < TPG; t++) acc[e][t] = 0.f;

        // Register pipeline: x double-buffered by column-group (j),
        // w double-buffered in 4-expert halves. No LDS -> no occupancy cap.
        float4 xA[TPG], xB[TPG], wA[4], wB[4];
#pragma unroll
        for (int t = 0; t < TPG; t++) xA[t] = xp[t * HV];
#pragma unroll
        for (int t = 0; t < TPG; t++) xB[t] = xp[t * HV + 64];
#pragma unroll
        for (int q = 0; q < 4; q++) wA[q] = wp[q * HV];
#pragma unroll
        for (int q = 0; q < 4; q++) wB[q] = wp[(4 + q) * HV];

#pragma unroll
        for (int j = 0; j < 8; j++) {
            float4* xc = (j & 1) ? xB : xA;
            // experts 0..3 with current x-group
#pragma unroll
            for (int q = 0; q < 4; q++) {
                const float4 wr = wA[q];
#pragma unroll
                for (int t = 0; t < TPG; t++) {
                    acc[q][t] = fmaf(xc[t].x, wr.x, acc[q][t]);
                    acc[q][t] = fmaf(xc[t].y, wr.y, acc[q][t]);
                    acc[q][t] = fmaf(xc[t].z, wr.z, acc[q][t]);
                    acc[q][t] = fmaf(xc[t].w, wr.w, acc[q][t]);
                }
            }
            // refill wA for group j+1 (consumed one full group from now)
            if (j + 1 < 8) {
#pragma unroll
                for (int q = 0; q < 4; q++) wA[q] = wp[q * HV + (j + 1) * 64];
            }
            // experts 4..7
#pragma unroll
            for (int q = 0; q < 4; q++) {
                const float4 wr = wB[q];
#pragma unroll
                for (int t = 0; t < TPG; t++) {
                    acc[4 + q][t] = fmaf(xc[t].x, wr.x, acc[4 + q][t]);
                    acc[4 + q][t] = fmaf(xc[t].y, wr.y, acc[4 + q][t]);
                    acc[4 + q][t] = fmaf(xc[t].z, wr.z, acc[4 + q][t]);
                    acc[4 + q][t] = fmaf(xc[t].w, wr.w, acc[4 + q][t]);
                }
            }
            if (j + 1 < 8) {
#pragma unroll
                for (int q = 0; q < 4; q++) wB[q] = wp[(4 + q) * HV + (j + 1) * 64];
            }
            // refill the x buffer just consumed with group j+2 (distance-2 cover)
            if (j + 2 < 8) {
#pragma unroll
                for (int t = 0; t < TPG; t++) xc[t] = xp[t * HV + (j + 2) * 64];
            }
        }

        // tree-reduce across the 64 lanes (all lanes end with the sum)
#pragma unroll
        for (int e = 0; e < NE; e++)
#pragma unroll
            for (int t = 0; t < TPG; t++) {
                float v = acc[e][t];
#pragma unroll
                for (int off = 32; off >= 1; off >>= 1)
                    v += __shfl_xor(v, off, 64);
                acc[e][t] = v;
            }

        float pi_loc[NE], cnt_loc[NE];
#pragma unroll
        for (int e = 0; e < NE; e++) { pi_loc[e] = 0.f; cnt_loc[e] = 0.f; }

#pragma unroll
        for (int t = 0; t < TPG; t++) {
            float l[NE];
#pragma unroll
            for (int e = 0; e < NE; e++) l[e] = acc[e][t];
            float m = l[0];
#pragma unroll
            for (int e = 1; e < NE; e++) m = fmaxf(m, l[e]);
            float s[NE];
            float sum = 0.f;
#pragma unroll
            for (int e = 0; e < NE; e++) { s[e] = __expf(l[e] - m); sum += s[e]; }
            const float rs = __builtin_amdgcn_rcpf(sum);
#pragma unroll
            for (int e = 0; e < NE; e++) s[e] = s[e] * rs;

            float b1 = -1.f, b2 = -1.f;
            int   i1 = 0,    i2 = 0;
#pragma unroll
            for (int e = 0; e < NE; e++) {
                if (s[e] > b1) { b2 = b1; i2 = i1; b1 = s[e]; i1 = e; }
                else if (s[e] > b2) { b2 = s[e]; i2 = e; }
            }

            if (lane == t) {
                const int tok = t0 + t;
                out[tok * 2 + 0]             = (float)i1;
                out[tok * 2 + 1]             = (float)i2;
                out[2 * T_TOK + tok * 2 + 0] = b1;
                out[2 * T_TOK + tok * 2 + 1] = b2;
            }
            const float sel = (lane == t) ? 1.f : 0.f;
#pragma unroll
            for (int e = 0; e < NE; e++) {
                pi_loc[e]  += sel * s[e];
                cnt_loc[e] += sel * (((i1 == e) ? 1.f : 0.f) + ((i2 == e) ? 1.f : 0.f));
            }
        }

        if (lane < TPG) {
#pragma unroll
            for (int e = 0; e < NE; e++) {
                atomicAdd(&s_pi[e],  pi_loc[e]);
                atomicAdd(&s_cnt[e], cnt_loc[e]);
            }
        }
        __syncthreads();
        if (tid < NE) {
            ws[blockIdx.x * 16 + tid]     = s_pi[tid];
            ws[blockIdx.x * 16 + 8 + tid] = s_cnt[tid];
        }
    }
}

__global__ __launch_bounds__(256) void gate_aux(
    const float* __restrict__ ws, float* __restrict__ out)
{
    __shared__ float s_pi[NE];
    __shared__ float s_cnt[NE];
    const int tid = threadIdx.x;
    if (tid < NE) { s_pi[tid] = 0.f; s_cnt[tid] = 0.f; }
    __syncthreads();

    float pi[NE], cnt[NE];
#pragma unroll
    for (int e = 0; e < NE; e++) { pi[e] = 0.f; cnt[e] = 0.f; }

    for (int b = tid; b < NBLK; b += 256) {
        const float4* p = (const float4*)(ws + b * 16);
        float4 a0 = p[0], a1 = p[1], a2 = p[2], a3 = p[3];
        pi[0] += a0.x; pi[1] += a0.y; pi[2] += a0.z; pi[3] += a0.w;
        pi[4] += a1.x; pi[5] += a1.y; pi[6] += a1.z; pi[7] += a1.w;
        cnt[0] += a2.x; cnt[1] += a2.y; cnt[2] += a2.z; cnt[3] += a2.w;
        cnt[4] += a3.x; cnt[5] += a3.y; cnt[6] += a3.z; cnt[7] += a3.w;
    }

#pragma unroll
    for (int e = 0; e < NE; e++) {
#pragma unroll
        for (int off = 32; off >= 1; off >>= 1) {
            pi[e]  += __shfl_xor(pi[e],  off, 64);
            cnt[e] += __shfl_xor(cnt[e], off, 64);
        }
    }
    if ((tid & 63) == 0) {
#pragma unroll
        for (int e = 0; e < NE; e++) {
            atomicAdd(&s_pi[e],  pi[e]);
            atomicAdd(&s_cnt[e], cnt[e]);
        }
    }
    __syncthreads();

    if (tid == 0) {
        float aux = 0.f;
#pragma unroll
        for (int e = 0; e < NE; e++) {
            const float Pi = s_pi[e] / (float)T_TOK;
            const float ce = s_cnt[e] / (float)(T_TOK * TOPK);
            aux += Pi * ce * (float)NE;
        }
        out[4 * T_TOK] = aux * ALPHA;
    }
}

extern "C" void kernel_launch(void* const* d_in, const int* in_sizes, int n_in,
                              void* d_out, int out_size, void* d_ws, size_t ws_size,
                              hipStream_t stream) {
    const float* x = (const float*)d_in[0];
    const float* w = (const float*)d_in[1];
    float* out = (float*)d_out;
    float* ws  = (float*)d_ws;

    gate_main<<<NBLK, 256, 0, stream>>>(x, w, out, ws);
    gate_aux<<<1, 256, 0, stream>>>(ws, out);
}

// Round 6
// 208.232 us; speedup vs baseline: 1.1787x; 1.1787x over previous
//
#include <hip/hip_runtime.h>

#define T_TOK 16384
#define H 2048
#define HV (H / 4)       // float4 per row = 512
#define NE 8
#define TPG 4            // tokens per wave
#define ALPHA 0.01f
#define TOPK 2
#define NBLK 1024        // 1024 blk * 4 waves * 4 tok = 16384 tokens

// out layout (floats): [0, 2T) idx as float, [2T, 4T) weights, [4T] aux loss
// ws layout (floats):  per-block partials, ws[b*16 + e] = sum(scores_e),
//                      ws[b*16 + 8 + e] = topk count_e

__global__ __launch_bounds__(256, 4) void gate_main(
    const float* __restrict__ x, const float* __restrict__ w,
    float* __restrict__ out, float* __restrict__ ws)
{
    __shared__ float s_pi[NE];
    __shared__ float s_cnt[NE];

    const int tid  = threadIdx.x;
    const int lane = tid & 63;
    const int wave = tid >> 6;
    const int t0   = (blockIdx.x * 4 + wave) * TPG;

    const float4* __restrict__ xv = (const float4*)x;
    const float4* __restrict__ wv = (const float4*)w;
    const float4* xp = xv + (size_t)t0 * HV + lane;
    const float4* wp = wv + lane;

    if (tid < NE) { s_pi[tid] = 0.f; s_cnt[tid] = 0.f; }
    __syncthreads();

    float acc[NE][TPG];
#pragma unroll
    for (int e = 0; e < NE; e++)
#pragma unroll
        for (int t = 0; t < TPG; t++) acc[e][t] = 0.f;

    // Register pipeline: x double-buffered by column-group (j),
    // w double-buffered in 4-expert halves. No LDS -> 16 waves/CU.
    float4 xA[TPG], xB[TPG], wA[4], wB[4];
#pragma unroll
    for (int t = 0; t < TPG; t++) xA[t] = xp[t * HV];
#pragma unroll
    for (int t = 0; t < TPG; t++) xB[t] = xp[t * HV + 64];
#pragma unroll
    for (int q = 0; q < 4; q++) wA[q] = wp[q * HV];
#pragma unroll
    for (int q = 0; q < 4; q++) wB[q] = wp[(4 + q) * HV];

#pragma unroll
    for (int j = 0; j < 8; j++) {
        float4* xc = (j & 1) ? xB : xA;
        // experts 0..3 with current x-group
#pragma unroll
        for (int q = 0; q < 4; q++) {
            const float4 wr = wA[q];
#pragma unroll
            for (int t = 0; t < TPG; t++) {
                acc[q][t] = fmaf(xc[t].x, wr.x, acc[q][t]);
                acc[q][t] = fmaf(xc[t].y, wr.y, acc[q][t]);
                acc[q][t] = fmaf(xc[t].z, wr.z, acc[q][t]);
                acc[q][t] = fmaf(xc[t].w, wr.w, acc[q][t]);
            }
        }
        if (j + 1 < 8) {
#pragma unroll
            for (int q = 0; q < 4; q++) wA[q] = wp[q * HV + (j + 1) * 64];
        }
        // experts 4..7
#pragma unroll
        for (int q = 0; q < 4; q++) {
            const float4 wr = wB[q];
#pragma unroll
            for (int t = 0; t < TPG; t++) {
                acc[4 + q][t] = fmaf(xc[t].x, wr.x, acc[4 + q][t]);
                acc[4 + q][t] = fmaf(xc[t].y, wr.y, acc[4 + q][t]);
                acc[4 + q][t] = fmaf(xc[t].z, wr.z, acc[4 + q][t]);
                acc[4 + q][t] = fmaf(xc[t].w, wr.w, acc[4 + q][t]);
            }
        }
        if (j + 1 < 8) {
#pragma unroll
            for (int q = 0; q < 4; q++) wB[q] = wp[(4 + q) * HV + (j + 1) * 64];
        }
        // refill the x buffer just consumed with group j+2 (distance-2 cover)
        if (j + 2 < 8) {
#pragma unroll
            for (int t = 0; t < TPG; t++) xc[t] = xp[t * HV + (j + 2) * 64];
        }
    }

    // tree-reduce across the 64 lanes (all lanes end with the sum)
#pragma unroll
    for (int e = 0; e < NE; e++)
#pragma unroll
        for (int t = 0; t < TPG; t++) {
            float v = acc[e][t];
#pragma unroll
            for (int off = 32; off >= 1; off >>= 1)
                v += __shfl_xor(v, off, 64);
            acc[e][t] = v;
        }

    float pi_loc[NE], cnt_loc[NE];
#pragma unroll
    for (int e = 0; e < NE; e++) { pi_loc[e] = 0.f; cnt_loc[e] = 0.f; }

#pragma unroll
    for (int t = 0; t < TPG; t++) {
        float l[NE];
#pragma unroll
        for (int e = 0; e < NE; e++) l[e] = acc[e][t];
        float m = l[0];
#pragma unroll
        for (int e = 1; e < NE; e++) m = fmaxf(m, l[e]);
        float s[NE];
        float sum = 0.f;
#pragma unroll
        for (int e = 0; e < NE; e++) { s[e] = __expf(l[e] - m); sum += s[e]; }
        const float rs = __builtin_amdgcn_rcpf(sum);
#pragma unroll
        for (int e = 0; e < NE; e++) s[e] = s[e] * rs;

        // top-2, ties -> lower index (strict > scan)
        float b1 = -1.f, b2 = -1.f;
        int   i1 = 0,    i2 = 0;
#pragma unroll
        for (int e = 0; e < NE; e++) {
            if (s[e] > b1) { b2 = b1; i2 = i1; b1 = s[e]; i1 = e; }
            else if (s[e] > b2) { b2 = s[e]; i2 = e; }
        }

        if (lane == t) {
            const int tok = t0 + t;
            *(float2*)(out + tok * 2)             = make_float2((float)i1, (float)i2);
            *(float2*)(out + 2 * T_TOK + tok * 2) = make_float2(b1, b2);
        }
        const float sel = (lane == t) ? 1.f : 0.f;
#pragma unroll
        for (int e = 0; e < NE; e++) {
            pi_loc[e]  += sel * s[e];
            cnt_loc[e] += sel * (((i1 == e) ? 1.f : 0.f) + ((i2 == e) ? 1.f : 0.f));
        }
    }

    // lanes 0..TPG-1 hold nonzero partials; fold into LDS (block-local)
    if (lane < TPG) {
#pragma unroll
        for (int e = 0; e < NE; e++) {
            atomicAdd(&s_pi[e],  pi_loc[e]);
            atomicAdd(&s_cnt[e], cnt_loc[e]);
        }
    }
    __syncthreads();
    // per-block partials: plain coalesced stores, NO global atomics
    if (tid < NE) {
        ws[blockIdx.x * 16 + tid]     = s_pi[tid];
        ws[blockIdx.x * 16 + 8 + tid] = s_cnt[tid];
    }
}

__global__ __launch_bounds__(256) void gate_aux(
    const float* __restrict__ ws, float* __restrict__ out)
{
    __shared__ float s_pi[NE];
    __shared__ float s_cnt[NE];
    const int tid = threadIdx.x;
    if (tid < NE) { s_pi[tid] = 0.f; s_cnt[tid] = 0.f; }
    __syncthreads();

    float pi[NE], cnt[NE];
#pragma unroll
    for (int e = 0; e < NE; e++) { pi[e] = 0.f; cnt[e] = 0.f; }

    for (int b = tid; b < NBLK; b += 256) {
        const float4* p = (const float4*)(ws + b * 16);
        float4 a0 = p[0], a1 = p[1], a2 = p[2], a3 = p[3];
        pi[0] += a0.x; pi[1] += a0.y; pi[2] += a0.z; pi[3] += a0.w;
        pi[4] += a1.x; pi[5] += a1.y; pi[6] += a1.z; pi[7] += a1.w;
        cnt[0] += a2.x; cnt[1] += a2.y; cnt[2] += a2.z; cnt[3] += a2.w;
        cnt[4] += a3.x; cnt[5] += a3.y; cnt[6] += a3.z; cnt[7] += a3.w;
    }

#pragma unroll
    for (int e = 0; e < NE; e++) {
#pragma unroll
        for (int off = 32; off >= 1; off >>= 1) {
            pi[e]  += __shfl_xor(pi[e],  off, 64);
            cnt[e] += __shfl_xor(cnt[e], off, 64);
        }
    }
    if ((tid & 63) == 0) {
#pragma unroll
        for (int e = 0; e < NE; e++) {
            atomicAdd(&s_pi[e],  pi[e]);
            atomicAdd(&s_cnt[e], cnt[e]);
        }
    }
    __syncthreads();

    if (tid == 0) {
        float aux = 0.f;
#pragma unroll
        for (int e = 0; e < NE; e++) {
            const float Pi = s_pi[e] / (float)T_TOK;
            const float ce = s_cnt[e] / (float)(T_TOK * TOPK);
            aux += Pi * ce * (float)NE;
        }
        out[4 * T_TOK] = aux * ALPHA;
    }
}

extern "C" void kernel_launch(void* const* d_in, const int* in_sizes, int n_in,
                              void* d_out, int out_size, void* d_ws, size_t ws_size,
                              hipStream_t stream) {
    const float* x = (const float*)d_in[0];
    const float* w = (const float*)d_in[1];
    float* out = (float*)d_out;
    float* ws  = (float*)d_ws;

    gate_main<<<NBLK, 256, 0, stream>>>(x, w, out, ws);
    gate_aux<<<1, 256, 0, stream>>>(ws, out);
}

// Round 7
// 207.909 us; speedup vs baseline: 1.1806x; 1.0016x over previous
//
#include <hip/hip_runtime.h>

#define T_TOK 16384
#define H 2048
#define HV (H / 4)       // float4 per row = 512
#define NE 8
#define TPG 4            // tokens per wave
#define ALPHA 0.01f
#define TOPK 2
#define NBLK 1024        // 1024 blk * 4 waves * 4 tok = 16384 tokens

// out layout (floats): [0, 2T) idx as float, [2T, 4T) weights, [4T] aux loss
// ws layout (floats):  per-block partials, ws[b*16 + e] = sum(scores_e),
//                      ws[b*16 + 8 + e] = topk count_e

__global__ __launch_bounds__(256, 4) void gate_main(
    const float* __restrict__ x, const float* __restrict__ w,
    float* __restrict__ out, float* __restrict__ ws)
{
    __shared__ float s_pi[NE];
    __shared__ float s_cnt[NE];

    const int tid  = threadIdx.x;
    const int lane = tid & 63;
    const int wave = tid >> 6;
    const int gw   = blockIdx.x * 4 + wave;
    const int t0   = gw * TPG;

    // Channel-decorrelation phase: each wave walks the 8 column-groups in a
    // rotated order so concurrent waves cover all 1KB column slices at once
    // (otherwise all waves hit the same 1/8 of the HBM/MALL channels in
    // lockstep -> ~2 TB/s camping ceiling observed in r3-r6).
    const int phase = gw & 7;
#define COL(j) ((((j) + phase) & 7) * 64)

    const float4* __restrict__ xv = (const float4*)x;
    const float4* __restrict__ wv = (const float4*)w;
    const float4* xp = xv + (size_t)t0 * HV + lane;
    const float4* wp = wv + lane;

    if (tid < NE) { s_pi[tid] = 0.f; s_cnt[tid] = 0.f; }
    __syncthreads();

    float acc[NE][TPG];
#pragma unroll
    for (int e = 0; e < NE; e++)
#pragma unroll
        for (int t = 0; t < TPG; t++) acc[e][t] = 0.f;

    // Register pipeline: x double-buffered by column-group (j),
    // w double-buffered in 4-expert halves. No LDS -> 16 waves/CU.
    float4 xA[TPG], xB[TPG], wA[4], wB[4];
#pragma unroll
    for (int t = 0; t < TPG; t++) xA[t] = xp[t * HV + COL(0)];
#pragma unroll
    for (int t = 0; t < TPG; t++) xB[t] = xp[t * HV + COL(1)];
#pragma unroll
    for (int q = 0; q < 4; q++) wA[q] = wp[q * HV + COL(0)];
#pragma unroll
    for (int q = 0; q < 4; q++) wB[q] = wp[(4 + q) * HV + COL(0)];

#pragma unroll
    for (int j = 0; j < 8; j++) {
        float4* xc = (j & 1) ? xB : xA;
        // experts 0..3 with current x-group
#pragma unroll
        for (int q = 0; q < 4; q++) {
            const float4 wr = wA[q];
#pragma unroll
            for (int t = 0; t < TPG; t++) {
                acc[q][t] = fmaf(xc[t].x, wr.x, acc[q][t]);
                acc[q][t] = fmaf(xc[t].y, wr.y, acc[q][t]);
                acc[q][t] = fmaf(xc[t].z, wr.z, acc[q][t]);
                acc[q][t] = fmaf(xc[t].w, wr.w, acc[q][t]);
            }
        }
        if (j + 1 < 8) {
#pragma unroll
            for (int q = 0; q < 4; q++) wA[q] = wp[q * HV + COL(j + 1)];
        }
        // experts 4..7
#pragma unroll
        for (int q = 0; q < 4; q++) {
            const float4 wr = wB[q];
#pragma unroll
            for (int t = 0; t < TPG; t++) {
                acc[4 + q][t] = fmaf(xc[t].x, wr.x, acc[4 + q][t]);
                acc[4 + q][t] = fmaf(xc[t].y, wr.y, acc[4 + q][t]);
                acc[4 + q][t] = fmaf(xc[t].z, wr.z, acc[4 + q][t]);
                acc[4 + q][t] = fmaf(xc[t].w, wr.w, acc[4 + q][t]);
            }
        }
        if (j + 1 < 8) {
#pragma unroll
            for (int q = 0; q < 4; q++) wB[q] = wp[(4 + q) * HV + COL(j + 1)];
        }
        // refill the x buffer just consumed with group j+2 (distance-2 cover)
        if (j + 2 < 8) {
#pragma unroll
            for (int t = 0; t < TPG; t++) xc[t] = xp[t * HV + COL(j + 2)];
        }
    }

    // tree-reduce across the 64 lanes (all lanes end with the sum)
#pragma unroll
    for (int e = 0; e < NE; e++)
#pragma unroll
        for (int t = 0; t < TPG; t++) {
            float v = acc[e][t];
#pragma unroll
            for (int off = 32; off >= 1; off >>= 1)
                v += __shfl_xor(v, off, 64);
            acc[e][t] = v;
        }

    float pi_loc[NE], cnt_loc[NE];
#pragma unroll
    for (int e = 0; e < NE; e++) { pi_loc[e] = 0.f; cnt_loc[e] = 0.f; }

#pragma unroll
    for (int t = 0; t < TPG; t++) {
        float l[NE];
#pragma unroll
        for (int e = 0; e < NE; e++) l[e] = acc[e][t];
        float m = l[0];
#pragma unroll
        for (int e = 1; e < NE; e++) m = fmaxf(m, l[e]);
        float s[NE];
        float sum = 0.f;
#pragma unroll
        for (int e = 0; e < NE; e++) { s[e] = __expf(l[e] - m); sum += s[e]; }
        const float rs = __builtin_amdgcn_rcpf(sum);
#pragma unroll
        for (int e = 0; e < NE; e++) s[e] = s[e] * rs;

        // top-2, ties -> lower index (strict > scan)
        float b1 = -1.f, b2 = -1.f;
        int   i1 = 0,    i2 = 0;
#pragma unroll
        for (int e = 0; e < NE; e++) {
            if (s[e] > b1) { b2 = b1; i2 = i1; b1 = s[e]; i1 = e; }
            else if (s[e] > b2) { b2 = s[e]; i2 = e; }
        }

        if (lane == t) {
            const int tok = t0 + t;
            *(float2*)(out + tok * 2)             = make_float2((float)i1, (float)i2);
            *(float2*)(out + 2 * T_TOK + tok * 2) = make_float2(b1, b2);
        }
        const float sel = (lane == t) ? 1.f : 0.f;
#pragma unroll
        for (int e = 0; e < NE; e++) {
            pi_loc[e]  += sel * s[e];
            cnt_loc[e] += sel * (((i1 == e) ? 1.f : 0.f) + ((i2 == e) ? 1.f : 0.f));
        }
    }

    // lanes 0..TPG-1 hold nonzero partials; fold into LDS (block-local)
    if (lane < TPG) {
#pragma unroll
        for (int e = 0; e < NE; e++) {
            atomicAdd(&s_pi[e],  pi_loc[e]);
            atomicAdd(&s_cnt[e], cnt_loc[e]);
        }
    }
    __syncthreads();
    // per-block partials: plain coalesced stores, NO global atomics
    if (tid < NE) {
        ws[blockIdx.x * 16 + tid]     = s_pi[tid];
        ws[blockIdx.x * 16 + 8 + tid] = s_cnt[tid];
    }
}

__global__ __launch_bounds__(256) void gate_aux(
    const float* __restrict__ ws, float* __restrict__ out)
{
    __shared__ float s_pi[NE];
    __shared__ float s_cnt[NE];
    const int tid = threadIdx.x;
    if (tid < NE) { s_pi[tid] = 0.f; s_cnt[tid] = 0.f; }
    __syncthreads();

    float pi[NE], cnt[NE];
#pragma unroll
    for (int e = 0; e < NE; e++) { pi[e] = 0.f; cnt[e] = 0.f; }

    for (int b = tid; b < NBLK; b += 256) {
        const float4* p = (const float4*)(ws + b * 16);
        float4 a0 = p[0], a1 = p[1], a2 = p[2], a3 = p[3];
        pi[0] += a0.x; pi[1] += a0.y; pi[2] += a0.z; pi[3] += a0.w;
        pi[4] += a1.x; pi[5] += a1.y; pi[6] += a1.z; pi[7] += a1.w;
        cnt[0] += a2.x; cnt[1] += a2.y; cnt[2] += a2.z; cnt[3] += a2.w;
        cnt[4] += a3.x; cnt[5] += a3.y; cnt[6] += a3.z; cnt[7] += a3.w;
    }

#pragma unroll
    for (int e = 0; e < NE; e++) {
#pragma unroll
        for (int off = 32; off >= 1; off >>= 1) {
            pi[e]  += __shfl_xor(pi[e],  off, 64);
            cnt[e] += __shfl_xor(cnt[e], off, 64);
        }
    }
    if ((tid & 63) == 0) {
#pragma unroll
        for (int e = 0; e < NE; e++) {
            atomicAdd(&s_pi[e],  pi[e]);
            atomicAdd(&s_cnt[e], cnt[e]);
        }
    }
    __syncthreads();

    if (tid == 0) {
        float aux = 0.f;
#pragma unroll
        for (int e = 0; e < NE; e++) {
            const float Pi = s_pi[e] / (float)T_TOK;
            const float ce = s_cnt[e] / (float)(T_TOK * TOPK);
            aux += Pi * ce * (float)NE;
        }
        out[4 * T_TOK] = aux * ALPHA;
    }
}

extern "C" void kernel_launch(void* const* d_in, const int* in_sizes, int n_in,
                              void* d_out, int out_size, void* d_ws, size_t ws_size,
                              hipStream_t stream) {
    const float* x = (const float*)d_in[0];
    const float* w = (const float*)d_in[1];
    float* out = (float*)d_out;
    float* ws  = (float*)d_ws;

    gate_main<<<NBLK, 256, 0, stream>>>(x, w, out, ws);
    gate_aux<<<1, 256, 0, stream>>>(ws, out);
}